// Round 17
// baseline (252.248 us; speedup 1.0000x reference)
//
#include <hip/hip_runtime.h>

// AGRU: B=2048, T=200, D=U=64, fp32. v16: dual-row interleaved rec (full file;
// r16 failed because r15 shipped a comment-only block -- never again).
// rec: ONE wave owns rows 2w,2w+1 interleaved in asm (row B ops fill row A
// latency gaps). Weights shared v64-191 (w_hr then w_hh via separate SGPR
// base reload); quad banks A=v192-223 B=v224-255, 8-read chunks with
// in-order lgkm counting; accs A=v32-39 B=v54-61; gates A/B alternated.
// All global addressing = SGPR base + 32-bit vaddr (SALU bumps).
// proj: r3/r11/r13 C version verbatim (~98us). All f32; gates v_exp/v_rcp.

typedef float f32x2 __attribute__((ext_vector_type(2)));

constexpr int BATCH = 2048;
constexpr int T_STEPS = 200;
constexpr int UDIM = 64;
constexpr int NROWS = BATCH * T_STEPS;   // 409600

#define STR_(x) #x
#define STR(x) STR_(x)

#define PTRLO(p) ((unsigned)(unsigned long long)(const void*)(p))
#define PTRHI(p) ((unsigned)(((unsigned long long)(const void*)(p)) >> 32))

__device__ __forceinline__ unsigned rfl(unsigned x) {
    return (unsigned)__builtin_amdgcn_readfirstlane((int)x);
}
__device__ __forceinline__ float lane_bcast(float v, int lane) {
    return __builtin_bit_cast(float, __builtin_amdgcn_readlane(__builtin_bit_cast(int, v), lane));
}
__device__ __forceinline__ float fast_sigmoid(float z) {
    return __builtin_amdgcn_rcpf(1.0f + __expf(-z));
}
__device__ __forceinline__ float fast_tanh(float z) {
    return 1.0f - 2.0f * __builtin_amdgcn_rcpf(__expf(2.0f * z) + 1.0f);
}

// ---- weight loads: 128 dword loads into v64..v191; saddr=s[56:57], vaddr=v14 (u*4) ----
#define WLD(R,O) "global_load_dword v" STR(R) ", v14, s[56:57] offset:" STR(O) "\n\t"
#define WBUMP "s_add_u32 s56, s56, 0x1000\n\ts_addc_u32 s57, s57, 0\n\t"

#define WIN16(R0,R1,R2,R3,R4,R5,R6,R7,R8,R9,R10,R11,R12,R13,R14,R15) \
  WLD(R0,0) WLD(R1,256) WLD(R2,512) WLD(R3,768) \
  WLD(R4,1024) WLD(R5,1280) WLD(R6,1536) WLD(R7,1792) \
  WLD(R8,2048) WLD(R9,2304) WLD(R10,2560) WLD(R11,2816) \
  WLD(R12,3072) WLD(R13,3328) WLD(R14,3584) WLD(R15,3840)

#define WLOAD_A \
  WIN16(64,65,66,67,68,69,70,71,72,73,74,75,76,77,78,79) WBUMP \
  WIN16(80,81,82,83,84,85,86,87,88,89,90,91,92,93,94,95) WBUMP \
  WIN16(96,97,98,99,100,101,102,103,104,105,106,107,108,109,110,111) WBUMP \
  WIN16(112,113,114,115,116,117,118,119,120,121,122,123,124,125,126,127)

#define WLOAD_B \
  WIN16(128,129,130,131,132,133,134,135,136,137,138,139,140,141,142,143) WBUMP \
  WIN16(144,145,146,147,148,149,150,151,152,153,154,155,156,157,158,159) WBUMP \
  WIN16(160,161,162,163,164,165,166,167,168,169,170,171,172,173,174,175) WBUMP \
  WIN16(176,177,178,179,180,181,182,183,184,185,186,187,188,189,190,191)

// ---- 8-read chunks (uniform addr broadcast); A base v29, B base v31 ----
#define READ_A_LO \
  "ds_read_b128 v[192:195], v29\n\t"            "ds_read_b128 v[196:199], v29 offset:16\n\t" \
  "ds_read_b128 v[200:203], v29 offset:32\n\t"  "ds_read_b128 v[204:207], v29 offset:48\n\t" \
  "ds_read_b128 v[208:211], v29 offset:64\n\t"  "ds_read_b128 v[212:215], v29 offset:80\n\t" \
  "ds_read_b128 v[216:219], v29 offset:96\n\t"  "ds_read_b128 v[220:223], v29 offset:112\n\t"
#define READ_A_HI \
  "ds_read_b128 v[192:195], v29 offset:128\n\t" "ds_read_b128 v[196:199], v29 offset:144\n\t" \
  "ds_read_b128 v[200:203], v29 offset:160\n\t" "ds_read_b128 v[204:207], v29 offset:176\n\t" \
  "ds_read_b128 v[208:211], v29 offset:192\n\t" "ds_read_b128 v[212:215], v29 offset:208\n\t" \
  "ds_read_b128 v[216:219], v29 offset:224\n\t" "ds_read_b128 v[220:223], v29 offset:240\n\t"
#define READ_B_LO \
  "ds_read_b128 v[224:227], v31\n\t"            "ds_read_b128 v[228:231], v31 offset:16\n\t" \
  "ds_read_b128 v[232:235], v31 offset:32\n\t"  "ds_read_b128 v[236:239], v31 offset:48\n\t" \
  "ds_read_b128 v[240:243], v31 offset:64\n\t"  "ds_read_b128 v[244:247], v31 offset:80\n\t" \
  "ds_read_b128 v[248:251], v31 offset:96\n\t"  "ds_read_b128 v[252:255], v31 offset:112\n\t"
#define READ_B_HI \
  "ds_read_b128 v[224:227], v31 offset:128\n\t" "ds_read_b128 v[228:231], v31 offset:144\n\t" \
  "ds_read_b128 v[232:235], v31 offset:160\n\t" "ds_read_b128 v[236:239], v31 offset:176\n\t" \
  "ds_read_b128 v[240:243], v31 offset:192\n\t" "ds_read_b128 v[244:247], v31 offset:208\n\t" \
  "ds_read_b128 v[248:251], v31 offset:224\n\t" "ds_read_b128 v[252:255], v31 offset:240\n\t"

// ---- consume one b128 quad: row A (accs v32-39) / row B (accs v54-61) ----
#define PKQ(W, Q0,Q1,Q2,Q3, A0,A1,A2,A3, B0,B1,B2,B3) \
  "s_waitcnt lgkmcnt(" STR(W) ")\n\t" \
  "v_pk_fma_f32 v[32:33], v[" STR(Q0) ":" STR(Q1) "], v[" STR(A0) ":" STR(A1) "], v[32:33]\n\t" \
  "v_pk_fma_f32 v[36:37], v[" STR(Q0) ":" STR(Q1) "], v[" STR(B0) ":" STR(B1) "], v[36:37]\n\t" \
  "v_pk_fma_f32 v[34:35], v[" STR(Q2) ":" STR(Q3) "], v[" STR(A2) ":" STR(A3) "], v[34:35]\n\t" \
  "v_pk_fma_f32 v[38:39], v[" STR(Q2) ":" STR(Q3) "], v[" STR(B2) ":" STR(B3) "], v[38:39]\n\t"
#define PKQB(W, Q0,Q1,Q2,Q3, A0,A1,A2,A3, B0,B1,B2,B3) \
  "s_waitcnt lgkmcnt(" STR(W) ")\n\t" \
  "v_pk_fma_f32 v[54:55], v[" STR(Q0) ":" STR(Q1) "], v[" STR(A0) ":" STR(A1) "], v[54:55]\n\t" \
  "v_pk_fma_f32 v[58:59], v[" STR(Q0) ":" STR(Q1) "], v[" STR(B0) ":" STR(B1) "], v[58:59]\n\t" \
  "v_pk_fma_f32 v[56:57], v[" STR(Q2) ":" STR(Q3) "], v[" STR(A2) ":" STR(A3) "], v[56:57]\n\t" \
  "v_pk_fma_f32 v[60:61], v[" STR(Q2) ":" STR(Q3) "], v[" STR(B2) ":" STR(B3) "], v[60:61]\n\t"

#define CONSUME_A_LO \
  PKQ(15, 192,193,194,195,  64,65,66,67,     128,129,130,131) \
  PKQ(14, 196,197,198,199,  68,69,70,71,     132,133,134,135) \
  PKQ(13, 200,201,202,203,  72,73,74,75,     136,137,138,139) \
  PKQ(12, 204,205,206,207,  76,77,78,79,     140,141,142,143) \
  PKQ(11, 208,209,210,211,  80,81,82,83,     144,145,146,147) \
  PKQ(10, 212,213,214,215,  84,85,86,87,     148,149,150,151) \
  PKQ(9,  216,217,218,219,  88,89,90,91,     152,153,154,155) \
  PKQ(8,  220,221,222,223,  92,93,94,95,     156,157,158,159)
#define CONSUME_B_LO \
  PKQB(15, 224,225,226,227,  64,65,66,67,     128,129,130,131) \
  PKQB(14, 228,229,230,231,  68,69,70,71,     132,133,134,135) \
  PKQB(13, 232,233,234,235,  72,73,74,75,     136,137,138,139) \
  PKQB(12, 236,237,238,239,  76,77,78,79,     140,141,142,143) \
  PKQB(11, 240,241,242,243,  80,81,82,83,     144,145,146,147) \
  PKQB(10, 244,245,246,247,  84,85,86,87,     148,149,150,151) \
  PKQB(9,  248,249,250,251,  88,89,90,91,     152,153,154,155) \
  PKQB(8,  252,253,254,255,  92,93,94,95,     156,157,158,159)
#define CONSUME_A_HI \
  PKQ(15, 192,193,194,195,  96,97,98,99,     160,161,162,163) \
  PKQ(14, 196,197,198,199,  100,101,102,103, 164,165,166,167) \
  PKQ(13, 200,201,202,203,  104,105,106,107, 168,169,170,171) \
  PKQ(12, 204,205,206,207,  108,109,110,111, 172,173,174,175) \
  PKQ(11, 208,209,210,211,  112,113,114,115, 176,177,178,179) \
  PKQ(10, 212,213,214,215,  116,117,118,119, 180,181,182,183) \
  PKQ(9,  216,217,218,219,  120,121,122,123, 184,185,186,187) \
  PKQ(8,  220,221,222,223,  124,125,126,127, 188,189,190,191)
#define CONSUME_B_HI \
  PKQB(7,  224,225,226,227,  96,97,98,99,     160,161,162,163) \
  PKQB(6,  228,229,230,231,  100,101,102,103, 164,165,166,167) \
  PKQB(5,  232,233,234,235,  104,105,106,107, 168,169,170,171) \
  PKQB(4,  236,237,238,239,  108,109,110,111, 172,173,174,175) \
  PKQB(3,  240,241,242,243,  112,113,114,115, 176,177,178,179) \
  PKQB(2,  244,245,246,247,  116,117,118,119, 180,181,182,183) \
  PKQB(1,  248,249,250,251,  120,121,122,123, 184,185,186,187) \
  PKQB(0,  252,253,254,255,  124,125,126,127, 188,189,190,191)

#define ACC_ZERO_AB \
  "v_mov_b32 v32, 0\n\t" "v_mov_b32 v33, 0\n\t" "v_mov_b32 v34, 0\n\t" "v_mov_b32 v35, 0\n\t" \
  "v_mov_b32 v36, 0\n\t" "v_mov_b32 v37, 0\n\t" "v_mov_b32 v38, 0\n\t" "v_mov_b32 v39, 0\n\t" \
  "v_mov_b32 v54, 0\n\t" "v_mov_b32 v55, 0\n\t" "v_mov_b32 v56, 0\n\t" "v_mov_b32 v57, 0\n\t" \
  "v_mov_b32 v58, 0\n\t" "v_mov_b32 v59, 0\n\t" "v_mov_b32 v60, 0\n\t" "v_mov_b32 v61, 0\n\t"

#define REC_CLOBBERS \
  "v8","v9","v12","v13","v14","v15","v16", \
  "v24","v25","v26","v27","v28","v29","v30","v31", \
  "v32","v33","v34","v35","v36","v37","v38","v39", \
  "v40","v41","v42","v43","v44","v45","v46","v47","v48","v49","v50", \
  "v51","v52","v53","v54","v55","v56","v57","v58","v59","v60","v61","v62", \
  "v64","v65","v66","v67","v68","v69","v70","v71", \
  "v72","v73","v74","v75","v76","v77","v78","v79", \
  "v80","v81","v82","v83","v84","v85","v86","v87", \
  "v88","v89","v90","v91","v92","v93","v94","v95", \
  "v96","v97","v98","v99","v100","v101","v102","v103", \
  "v104","v105","v106","v107","v108","v109","v110","v111", \
  "v112","v113","v114","v115","v116","v117","v118","v119", \
  "v120","v121","v122","v123","v124","v125","v126","v127", \
  "v128","v129","v130","v131","v132","v133","v134","v135", \
  "v136","v137","v138","v139","v140","v141","v142","v143", \
  "v144","v145","v146","v147","v148","v149","v150","v151", \
  "v152","v153","v154","v155","v156","v157","v158","v159", \
  "v160","v161","v162","v163","v164","v165","v166","v167", \
  "v168","v169","v170","v171","v172","v173","v174","v175", \
  "v176","v177","v178","v179","v180","v181","v182","v183", \
  "v184","v185","v186","v187","v188","v189","v190","v191", \
  "v192","v193","v194","v195","v196","v197","v198","v199", \
  "v200","v201","v202","v203","v204","v205","v206","v207", \
  "v208","v209","v210","v211","v212","v213","v214","v215", \
  "v216","v217","v218","v219","v220","v221","v222","v223", \
  "v224","v225","v226","v227","v228","v229","v230","v231", \
  "v232","v233","v234","v235","v236","v237","v238","v239", \
  "v240","v241","v242","v243","v244","v245","v246","v247", \
  "v248","v249","v250","v251","v252","v253","v254","v255", \
  "s40","s41","s42","s43","s44","s45","s46","s47", \
  "s52","s53","s54","s55","s56","s57","s60","s61","s62", \
  "vcc","scc","memory"

// ---------------- Kernel 2: recurrence (dual-row interleaved) -------------
// 256 blocks x 256 = 1024 waves (1/SIMD); rows 2w and 2w+1 per wave.
__global__ __launch_bounds__(256, 1) void rec_kernel(
    const f32x2* __restrict__ pre, const float* __restrict__ att,
    const float* __restrict__ h0,  const float* __restrict__ w_hr,
    const float* __restrict__ w_hh,const float* __restrict__ b_hh,
    float* __restrict__ out)
{
    const int u   = threadIdx.x & 63;
    const int wid = (int)((blockIdx.x * blockDim.x + threadIdx.x) >> 6);
    const int rA  = wid * 2;
    const int rB  = rA + 1;

    __shared__ __align__(16) float hbuf[4][2][UDIM];   // 2 KB: per-wave 2 rows
    const unsigned lrb = (unsigned)(unsigned long long)(&hbuf[threadIdx.x >> 6][0][0]);
    const unsigned lwa = lrb + 4u * (unsigned)u;

    const f32x2* pA = pre + (size_t)rA * T_STEPS * UDIM;
    const f32x2* pB = pre + (size_t)rB * T_STEPS * UDIM;
    const float* aA = att + (size_t)rA * T_STEPS;
    const float* aB = att + (size_t)rB * T_STEPS;
    float*       oA = out + (size_t)rA * T_STEPS * UDIM;
    float*       oB = out + (size_t)rB * T_STEPS * UDIM;

    const unsigned walo = rfl(PTRLO(w_hr)), wahi = rfl(PTRHI(w_hr));
    const unsigned whlo = rfl(PTRLO(w_hh)), whhi = rfl(PTRHI(w_hh));
    const unsigned pAlo = rfl(PTRLO(pA)), pAhi = rfl(PTRHI(pA));
    const unsigned pBlo = rfl(PTRLO(pB)), pBhi = rfl(PTRHI(pB));
    const unsigned aAlo = rfl(PTRLO(aA)), aAhi = rfl(PTRHI(aA));
    const unsigned aBlo = rfl(PTRLO(aB)), aBhi = rfl(PTRHI(aB));
    const unsigned oAlo = rfl(PTRLO(oA)), oAhi = rfl(PTRHI(oA));
    const unsigned oBlo = rfl(PTRLO(oB)), oBhi = rfl(PTRHI(oB));

    const float h0A = h0[(size_t)rA * UDIM + u];
    const float h0B = h0[(size_t)rB * UDIM + u];
    const float bgv = b_hh[u];

    asm volatile(
        // ---- SGPR bases ----
        "s_mov_b32 s40, %[pAlo]\n\t" "s_mov_b32 s41, %[pAhi]\n\t"
        "s_mov_b32 s42, %[aAlo]\n\t" "s_mov_b32 s43, %[aAhi]\n\t"
        "s_mov_b32 s44, %[oAlo]\n\t" "s_mov_b32 s45, %[oAhi]\n\t"
        "s_mov_b32 s46, %[pBlo]\n\t" "s_mov_b32 s47, %[pBhi]\n\t"
        "s_mov_b32 s52, %[aBlo]\n\t" "s_mov_b32 s53, %[aBhi]\n\t"
        "s_mov_b32 s54, %[oBlo]\n\t" "s_mov_b32 s55, %[oBhi]\n\t"
        // ---- lane addressing ----
        "v_mov_b32 v28, %[lwa]\n\t"          // LDS write addr, row A
        "v_mov_b32 v29, %[lrb]\n\t"          // LDS read base, row A
        "v_add_u32 v30, 0x100, v28\n\t"      // write addr, row B
        "v_add_u32 v31, 0x100, v29\n\t"      // read base, row B
        "v_sub_u32 v14, v28, v29\n\t"        // u*4
        "v_lshlrev_b32 v12, 1, v14\n\t"      // u*8
        "v_mov_b32 v13, 0\n\t"               // uniform vaddr for att
        // ---- weights: w_hr -> v64..127, w_hh -> v128..191 ----
        "s_mov_b32 s56, %[walo]\n\t" "s_mov_b32 s57, %[wahi]\n\t"
        WLOAD_A
        "s_mov_b32 s56, %[whlo]\n\t" "s_mov_b32 s57, %[whhi]\n\t"
        WLOAD_B
        // ---- state ----
        "v_mov_b32 v8, %[h0A]\n\t"
        "v_mov_b32 v9, %[h0B]\n\t"
        "v_mov_b32 v27, %[bgv]\n\t"
        // ---- prologue: load t=0 (A pv,av + B pv,av); drain; copy; load t=1 ----
        "global_load_dwordx2 v[40:41], v12, s[40:41]\n\t"
        "global_load_dword v42, v13, s[42:43]\n\t"
        "global_load_dwordx2 v[24:25], v12, s[46:47]\n\t"
        "global_load_dword v26, v13, s[52:53]\n\t"
        "s_add_u32 s40, s40, 0x200\n\t" "s_addc_u32 s41, s41, 0\n\t"
        "s_add_u32 s46, s46, 0x200\n\t" "s_addc_u32 s47, s47, 0\n\t"
        "s_add_u32 s42, s42, 4\n\t"     "s_addc_u32 s43, s43, 0\n\t"
        "s_add_u32 s52, s52, 4\n\t"     "s_addc_u32 s53, s53, 0\n\t"
        "s_waitcnt vmcnt(0)\n\t"
        "v_mov_b32 v44, v40\n\t" "v_mov_b32 v45, v41\n\t" "v_mov_b32 v46, v42\n\t"
        "v_mov_b32 v48, v24\n\t" "v_mov_b32 v49, v25\n\t" "v_mov_b32 v47, v26\n\t"
        "global_load_dwordx2 v[40:41], v12, s[40:41]\n\t"
        "global_load_dword v42, v13, s[42:43]\n\t"
        "global_load_dwordx2 v[24:25], v12, s[46:47]\n\t"
        "global_load_dword v26, v13, s[52:53]\n\t"
        "s_add_u32 s40, s40, 0x200\n\t" "s_addc_u32 s41, s41, 0\n\t"
        "s_add_u32 s46, s46, 0x200\n\t" "s_addc_u32 s47, s47, 0\n\t"
        "s_add_u32 s42, s42, 4\n\t"     "s_addc_u32 s43, s43, 0\n\t"
        "s_add_u32 s52, s52, 4\n\t"     "s_addc_u32 s53, s53, 0\n\t"
        // ---- prologue LDS: write h0 A/B, drain, issue first chunks ----
        "ds_write_b32 v28, v8\n\t"
        "ds_write_b32 v30, v9\n\t"
        "s_waitcnt lgkmcnt(0)\n\t"
        READ_A_LO
        READ_B_LO
        "s_movk_i32 s60, 200\n\t"
        "Lrec%=:\n\t"
        ACC_ZERO_AB
        CONSUME_A_LO
        READ_A_HI
        CONSUME_B_LO
        READ_B_HI
        CONSUME_A_HI
        CONSUME_B_HI
        // ---- reduce (A/B interleaved) ----
        "v_add_f32 v51, v32, v33\n\t"
        "v_add_f32 v53, v54, v55\n\t"
        "v_add_f32 v52, v34, v35\n\t"
        "v_add_f32 v62, v56, v57\n\t"
        "v_add_f32 v51, v51, v52\n\t"      // sRA
        "v_add_f32 v53, v53, v62\n\t"      // sRB
        "v_add_f32 v52, v36, v37\n\t"
        "v_add_f32 v62, v58, v59\n\t"
        "v_add_f32 v15, v38, v39\n\t"
        "v_add_f32 v16, v60, v61\n\t"
        "v_add_f32 v52, v52, v15\n\t"      // sGA
        "v_add_f32 v62, v62, v16\n\t"      // sGB
        // ---- gates, A/B alternated (partner op fills trans latency) ----
        "v_add_f32 v51, v44, v51\n\t"      // zrA = pvA.x + sRA
        "v_add_f32 v53, v48, v53\n\t"      // zrB
        "v_add_f32 v52, v27, v52\n\t"      // sGA + bg
        "v_add_f32 v62, v27, v62\n\t"      // sGB + bg
        "v_mul_f32 v51, 0xbfb8aa3b, v51\n\t"
        "v_mul_f32 v53, 0xbfb8aa3b, v53\n\t"
        "v_exp_f32 v51, v51\n\t"
        "v_exp_f32 v53, v53\n\t"
        "s_nop 0\n\t"
        "v_add_f32 v51, 1.0, v51\n\t"
        "v_add_f32 v53, 1.0, v53\n\t"
        "v_rcp_f32 v51, v51\n\t"           // rA
        "v_rcp_f32 v53, v53\n\t"           // rB
        "s_nop 0\n\t"
        "v_mul_f32 v52, v51, v52\n\t"
        "v_mul_f32 v62, v53, v62\n\t"
        "v_add_f32 v52, v45, v52\n\t"      // zhA = pvA.y + rA*(sGA+bg)
        "v_add_f32 v62, v49, v62\n\t"      // zhB
        "v_mul_f32 v52, 0x4038aa3b, v52\n\t"
        "v_mul_f32 v62, 0x4038aa3b, v62\n\t"
        "v_exp_f32 v52, v52\n\t"
        "v_exp_f32 v62, v62\n\t"
        "s_nop 0\n\t"
        "v_add_f32 v52, 1.0, v52\n\t"
        "v_add_f32 v62, 1.0, v62\n\t"
        "v_rcp_f32 v52, v52\n\t"
        "v_rcp_f32 v62, v62\n\t"
        "s_nop 0\n\t"
        "v_fma_f32 v52, -2.0, v52, 1.0\n\t"   // hcA
        "v_fma_f32 v62, -2.0, v62, 1.0\n\t"   // hcB
        "v_sub_f32 v15, v52, v8\n\t"
        "v_sub_f32 v16, v62, v9\n\t"
        "v_fmac_f32 v8, v46, v15\n\t"      // hA += avA*(hcA-hA)
        "v_fmac_f32 v9, v47, v16\n\t"      // hB += avB*(hcB-hB)
        // ---- bottom memory phase ----
        "ds_write_b32 v28, v8\n\t"
        "ds_write_b32 v30, v9\n\t"
        "s_waitcnt vmcnt(5)\n\t"           // storeA(t-1) retired -> v43 free
        "v_mov_b32 v43, v8\n\t"
        "global_store_dword v14, v43, s[44:45]\n\t"
        "s_waitcnt vmcnt(5)\n\t"           // storeB(t-1) retired -> v50 free
        "v_mov_b32 v50, v9\n\t"
        "global_store_dword v14, v50, s[54:55]\n\t"
        "s_waitcnt vmcnt(2)\n\t"           // the 4 prefetch loads landed
        "v_mov_b32 v44, v40\n\t" "v_mov_b32 v45, v41\n\t" "v_mov_b32 v46, v42\n\t"
        "v_mov_b32 v48, v24\n\t" "v_mov_b32 v49, v25\n\t" "v_mov_b32 v47, v26\n\t"
        "global_load_dwordx2 v[40:41], v12, s[40:41]\n\t"
        "global_load_dword v42, v13, s[42:43]\n\t"
        "global_load_dwordx2 v[24:25], v12, s[46:47]\n\t"
        "global_load_dword v26, v13, s[52:53]\n\t"
        "s_sub_u32 s60, s60, 1\n\t"
        "s_cmp_ge_u32 s60, 3\n\t"
        "s_cselect_b32 s61, 0x200, 0\n\t"
        "s_cselect_b32 s62, 4, 0\n\t"
        "s_add_u32 s40, s40, s61\n\t" "s_addc_u32 s41, s41, 0\n\t"
        "s_add_u32 s46, s46, s61\n\t" "s_addc_u32 s47, s47, 0\n\t"
        "s_add_u32 s42, s42, s62\n\t" "s_addc_u32 s43, s43, 0\n\t"
        "s_add_u32 s52, s52, s62\n\t" "s_addc_u32 s53, s53, 0\n\t"
        "s_add_u32 s44, s44, 0x100\n\t" "s_addc_u32 s45, s45, 0\n\t"
        "s_add_u32 s54, s54, 0x100\n\t" "s_addc_u32 s55, s55, 0\n\t"
        "s_waitcnt lgkmcnt(0)\n\t"         // h writes drained
        READ_A_LO
        READ_B_LO
        "s_cmp_lg_u32 s60, 0\n\t"
        "s_cbranch_scc1 Lrec%=\n\t"
        "s_waitcnt vmcnt(0) lgkmcnt(0)\n\t"
        :
        : [walo]"s"(walo), [wahi]"s"(wahi),
          [whlo]"s"(whlo), [whhi]"s"(whhi),
          [pAlo]"s"(pAlo), [pAhi]"s"(pAhi),
          [aAlo]"s"(aAlo), [aAhi]"s"(aAhi),
          [oAlo]"s"(oAlo), [oAhi]"s"(oAhi),
          [pBlo]"s"(pBlo), [pBhi]"s"(pBhi),
          [aBlo]"s"(aBlo), [aBhi]"s"(aBhi),
          [oBlo]"s"(oBlo), [oBhi]"s"(oBhi),
          [h0A]"v"(h0A), [h0B]"v"(h0B), [bgv]"v"(bgv),
          [lwa]"v"(lwa), [lrb]"v"(lrb)
        : REC_CLOBBERS);
}

// ---------------- Kernel 1: projections (r3/r11/r13 verbatim) -------------
// 1024 blocks x 256 = 4096 waves; 409600 rows = 4096 waves * 25 groups * 4.
__global__ __launch_bounds__(256, 3) void proj_kernel(
    const float* __restrict__ x,     // [B*T,64]
    const float* __restrict__ w_ir,  // [64,64]
    const float* __restrict__ w_ih,  // [64,64]
    const float* __restrict__ b_ir,
    const float* __restrict__ b_hr,
    const float* __restrict__ b_ih,
    f32x2* __restrict__ pre)         // [B*T,64] of {pre_r, pre_h}
{
    const int u = threadIdx.x & 63;

    f32x2 w2[UDIM];
    #pragma unroll
    for (int j = 0; j < UDIM; ++j) {
        w2[j].x = w_ir[j * UDIM + u];   // coalesced 256B row reads
        w2[j].y = w_ih[j * UDIM + u];
    }
    const float br = b_ir[u] + b_hr[u];
    const float bh = b_ih[u];

    const int nwaves = (int)((gridDim.x * blockDim.x) >> 6);       // 4096
    const int wid = (int)((blockIdx.x * blockDim.x + threadIdx.x) >> 6);

    const int ngroups = NROWS / 4;                                  // 102400
    const float* xp = x + u;

    long r = (long)wid * 4;
    float xa = xp[(r + 0) * UDIM];
    float xb = xp[(r + 1) * UDIM];
    float xc = xp[(r + 2) * UDIM];
    float xd = xp[(r + 3) * UDIM];

    for (int g = wid; g < ngroups; g += nwaves) {
        const int gn = (g + nwaves < ngroups) ? (g + nwaves) : g;
        const long rn = (long)gn * 4;
        float na = xp[(rn + 0) * UDIM];
        float nb = xp[(rn + 1) * UDIM];
        float nc = xp[(rn + 2) * UDIM];
        float nd = xp[(rn + 3) * UDIM];

        f32x2* po = pre + (long)g * 4 * UDIM + u;

        #pragma unroll
        for (int k = 0; k < 4; ++k) {
            const float xv = (k == 0) ? xa : (k == 1) ? xb : (k == 2) ? xc : xd;
            f32x2 accA; accA.x = br;  accA.y = bh;
            f32x2 accB; accB.x = 0.f; accB.y = 0.f;
            #pragma unroll
            for (int j = 0; j < UDIM; j += 2) {
                const float s0 = lane_bcast(xv, j);
                const float s1 = lane_bcast(xv, j + 1);
                accA.x = fmaf(s0, w2[j].x,     accA.x);
                accA.y = fmaf(s0, w2[j].y,     accA.y);
                accB.x = fmaf(s1, w2[j + 1].x, accB.x);
                accB.y = fmaf(s1, w2[j + 1].y, accB.y);
            }
            f32x2 o; o.x = accA.x + accB.x; o.y = accA.y + accB.y;
            po[(long)k * UDIM] = o;     // global_store_dwordx2
        }

        xa = na; xb = nb; xc = nc; xd = nd;
    }
}

// ---------------- Fallback: fused kernel (small ws) ----------------
__global__ __launch_bounds__(256) void agru_fused_kernel(
    const float* __restrict__ x, const float* __restrict__ att,
    const float* __restrict__ h0,
    const float* __restrict__ w_ir, const float* __restrict__ w_hr,
    const float* __restrict__ b_ir, const float* __restrict__ b_hr,
    const float* __restrict__ w_ih, const float* __restrict__ w_hh,
    const float* __restrict__ b_ih, const float* __restrict__ b_hh,
    float* __restrict__ out)
{
    __shared__ float lds[4 * UDIM * UDIM];
    const int tid = threadIdx.x;
    #pragma unroll
    for (int i = 0; i < 16; ++i) {
        int e = tid + 256 * i;
        lds[e] = w_ir[e]; lds[4096 + e] = w_ih[e];
        lds[8192 + e] = w_hr[e]; lds[12288 + e] = w_hh[e];
    }
    __syncthreads();

    const int wave = tid >> 6;
    const int u = tid & 63;
    const int r0 = blockIdx.x * 8 + wave * 2;
    const int r1 = r0 + 1;

    float h_0 = h0[r0 * UDIM + u];
    float h_1 = h0[r1 * UDIM + u];
    const float bR = b_ir[u] + b_hr[u];
    const float bH = b_ih[u];
    const float bG = b_hh[u];

    const float* xp0 = x + (long)r0 * T_STEPS * UDIM + u;
    const float* xp1 = x + (long)r1 * T_STEPS * UDIM + u;
    const float* ap0 = att + (long)r0 * T_STEPS;
    const float* ap1 = att + (long)r1 * T_STEPS;
    float* op0 = out + (long)r0 * T_STEPS * UDIM + u;
    float* op1 = out + (long)r1 * T_STEPS * UDIM + u;

    float xv0 = xp0[0], xv1 = xp1[0], a0 = ap0[0], a1 = ap1[0];

    for (int t = 0; t < T_STEPS; ++t) {
        const int tn = (t + 1 < T_STEPS) ? (t + 1) : t;
        float nxv0 = xp0[(long)tn * UDIM], nxv1 = xp1[(long)tn * UDIM];
        float na0 = ap0[tn], na1 = ap1[tn];

        float accR0 = bR, accR1 = bR, accH0 = bH, accH1 = bH, accG0 = bG, accG1 = bG;
        #pragma unroll
        for (int j = 0; j < 64; ++j) {
            const float wir = lds[j * 64 + u];
            const float wih = lds[4096 + j * 64 + u];
            const float whr = lds[8192 + j * 64 + u];
            const float whh = lds[12288 + j * 64 + u];
            const float xj0 = lane_bcast(xv0, j);
            const float xj1 = lane_bcast(xv1, j);
            const float hj0 = lane_bcast(h_0, j);
            const float hj1 = lane_bcast(h_1, j);
            accR0 = fmaf(xj0, wir, accR0); accR0 = fmaf(hj0, whr, accR0);
            accH0 = fmaf(xj0, wih, accH0); accG0 = fmaf(hj0, whh, accG0);
            accR1 = fmaf(xj1, wir, accR1); accR1 = fmaf(hj1, whr, accR1);
            accH1 = fmaf(xj1, wih, accH1); accG1 = fmaf(hj1, whh, accG1);
        }
        const float r0g = fast_sigmoid(accR0);
        const float r1g = fast_sigmoid(accR1);
        const float hc0 = fast_tanh(fmaf(r0g, accG0, accH0));
        const float hc1 = fast_tanh(fmaf(r1g, accG1, accH1));
        h_0 = fmaf(a0, hc0 - h_0, h_0);
        h_1 = fmaf(a1, hc1 - h_1, h_1);
        op0[(long)t * UDIM] = h_0;
        op1[(long)t * UDIM] = h_1;
        xv0 = nxv0; xv1 = nxv1; a0 = na0; a1 = na1;
    }
}

extern "C" void kernel_launch(void* const* d_in, const int* in_sizes, int n_in,
                              void* d_out, int out_size, void* d_ws, size_t ws_size,
                              hipStream_t stream) {
    (void)in_sizes; (void)n_in; (void)out_size;

    const float* x    = (const float*)d_in[0];
    const float* att  = (const float*)d_in[1];
    const float* h0   = (const float*)d_in[2];
    const float* w_ir = (const float*)d_in[3];
    const float* w_hr = (const float*)d_in[4];
    const float* b_ir = (const float*)d_in[5];
    const float* b_hr = (const float*)d_in[6];
    const float* w_ih = (const float*)d_in[7];
    const float* w_hh = (const float*)d_in[8];
    const float* b_ih = (const float*)d_in[9];
    const float* b_hh = (const float*)d_in[10];
    float* out = (float*)d_out;

    const size_t pre_bytes = (size_t)NROWS * UDIM * sizeof(f32x2); // 210 MB

    if (ws_size >= pre_bytes) {
        f32x2* pre = (f32x2*)d_ws;
        proj_kernel<<<dim3(1024), dim3(256), 0, stream>>>(
            x, w_ir, w_ih, b_ir, b_hr, b_ih, pre);
        rec_kernel<<<dim3(256), dim3(256), 0, stream>>>(
            pre, att, h0, w_hr, w_hh, b_hh, out);
    } else {
        agru_fused_kernel<<<dim3(256), dim3(256), 0, stream>>>(
            x, att, h0, w_ir, w_hr, b_ir, b_hr, w_ih, w_hh, b_ih, b_hh, out);
    }
}

// Round 18
// 236.169 us; speedup vs baseline: 1.0681x; 1.0681x over previous
//
#include <hip/hip_runtime.h>

// AGRU: B=2048, T=200, D=U=64, fp32. v17.
//  - rec: r13/r15 single-row asm core VERBATIM (146us, verified; r17 proved
//    dual-row interleave is neutral -- both rows stall at the same phase).
//  - proj: NEW asm = 4-row-group LDS-broadcast. r14's asm proj failed by
//    paying ds_write->drain->read PER ROW; here one drain serves 4 rows,
//    row k+1's 16 uniform ds_read_b128 issue before row k's reduce, and
//    stores use per-row register pairs with a vmcnt ladder (7,7,7,7 / 4).
// All f32 (f16 diverges, r7). Gates via v_exp/v_rcp (absmax ~0.004).

typedef float f32x2 __attribute__((ext_vector_type(2)));

constexpr int BATCH = 2048;
constexpr int T_STEPS = 200;
constexpr int UDIM = 64;
constexpr int NROWS = BATCH * T_STEPS;   // 409600

#define STR_(x) #x
#define STR(x) STR_(x)

#define PTRLO(p) ((unsigned)(unsigned long long)(const void*)(p))
#define PTRHI(p) ((unsigned)(((unsigned long long)(const void*)(p)) >> 32))

__device__ __forceinline__ unsigned rfl(unsigned x) {
    return (unsigned)__builtin_amdgcn_readfirstlane((int)x);
}
__device__ __forceinline__ float lane_bcast(float v, int lane) {
    return __builtin_bit_cast(float, __builtin_amdgcn_readlane(__builtin_bit_cast(int, v), lane));
}
__device__ __forceinline__ float fast_sigmoid(float z) {
    return __builtin_amdgcn_rcpf(1.0f + __expf(-z));
}
__device__ __forceinline__ float fast_tanh(float z) {
    return 1.0f - 2.0f * __builtin_amdgcn_rcpf(__expf(2.0f * z) + 1.0f);
}

// ======================= shared DOT machinery =======================
// 16 uniform-address ds_read_b128 into v192..v255, base v29 + OFS
#define LDSREADS_AT(O0,O1,O2,O3,O4,O5,O6,O7,O8,O9,O10,O11,O12,O13,O14,O15) \
  "ds_read_b128 v[192:195], v29 offset:" STR(O0) "\n\t" \
  "ds_read_b128 v[196:199], v29 offset:" STR(O1) "\n\t" \
  "ds_read_b128 v[200:203], v29 offset:" STR(O2) "\n\t" \
  "ds_read_b128 v[204:207], v29 offset:" STR(O3) "\n\t" \
  "ds_read_b128 v[208:211], v29 offset:" STR(O4) "\n\t" \
  "ds_read_b128 v[212:215], v29 offset:" STR(O5) "\n\t" \
  "ds_read_b128 v[216:219], v29 offset:" STR(O6) "\n\t" \
  "ds_read_b128 v[220:223], v29 offset:" STR(O7) "\n\t" \
  "ds_read_b128 v[224:227], v29 offset:" STR(O8) "\n\t" \
  "ds_read_b128 v[228:231], v29 offset:" STR(O9) "\n\t" \
  "ds_read_b128 v[232:235], v29 offset:" STR(O10) "\n\t" \
  "ds_read_b128 v[236:239], v29 offset:" STR(O11) "\n\t" \
  "ds_read_b128 v[240:243], v29 offset:" STR(O12) "\n\t" \
  "ds_read_b128 v[244:247], v29 offset:" STR(O13) "\n\t" \
  "ds_read_b128 v[248:251], v29 offset:" STR(O14) "\n\t" \
  "ds_read_b128 v[252:255], v29 offset:" STR(O15) "\n\t"

#define LDSREADS  LDSREADS_AT(0,16,32,48,64,80,96,112,128,144,160,176,192,208,224,240)
#define PREADS1   LDSREADS_AT(256,272,288,304,320,336,352,368,384,400,416,432,448,464,480,496)
#define PREADS2   LDSREADS_AT(512,528,544,560,576,592,608,624,640,656,672,688,704,720,736,752)
#define PREADS3   LDSREADS_AT(768,784,800,816,832,848,864,880,896,912,928,944,960,976,992,1008)

#define PKQ(W, Q0,Q1,Q2,Q3, A0,A1,A2,A3, B0,B1,B2,B3) \
  "s_waitcnt lgkmcnt(" STR(W) ")\n\t" \
  "v_pk_fma_f32 v[32:33], v[" STR(Q0) ":" STR(Q1) "], v[" STR(A0) ":" STR(A1) "], v[32:33]\n\t" \
  "v_pk_fma_f32 v[36:37], v[" STR(Q0) ":" STR(Q1) "], v[" STR(B0) ":" STR(B1) "], v[36:37]\n\t" \
  "v_pk_fma_f32 v[34:35], v[" STR(Q2) ":" STR(Q3) "], v[" STR(A2) ":" STR(A3) "], v[34:35]\n\t" \
  "v_pk_fma_f32 v[38:39], v[" STR(Q2) ":" STR(Q3) "], v[" STR(B2) ":" STR(B3) "], v[38:39]\n\t"

#define DOTCONSUME \
  PKQ(15, 192,193,194,195,  64,65,66,67,     128,129,130,131) \
  PKQ(14, 196,197,198,199,  68,69,70,71,     132,133,134,135) \
  PKQ(13, 200,201,202,203,  72,73,74,75,     136,137,138,139) \
  PKQ(12, 204,205,206,207,  76,77,78,79,     140,141,142,143) \
  PKQ(11, 208,209,210,211,  80,81,82,83,     144,145,146,147) \
  PKQ(10, 212,213,214,215,  84,85,86,87,     148,149,150,151) \
  PKQ(9,  216,217,218,219,  88,89,90,91,     152,153,154,155) \
  PKQ(8,  220,221,222,223,  92,93,94,95,     156,157,158,159) \
  PKQ(7,  224,225,226,227,  96,97,98,99,     160,161,162,163) \
  PKQ(6,  228,229,230,231,  100,101,102,103, 164,165,166,167) \
  PKQ(5,  232,233,234,235,  104,105,106,107, 168,169,170,171) \
  PKQ(4,  236,237,238,239,  108,109,110,111, 172,173,174,175) \
  PKQ(3,  240,241,242,243,  112,113,114,115, 176,177,178,179) \
  PKQ(2,  244,245,246,247,  116,117,118,119, 180,181,182,183) \
  PKQ(1,  248,249,250,251,  120,121,122,123, 184,185,186,187) \
  PKQ(0,  252,253,254,255,  124,125,126,127, 188,189,190,191)

#define ACC_ZERO \
  "v_mov_b32 v32, 0\n\t" "v_mov_b32 v33, 0\n\t" \
  "v_mov_b32 v34, 0\n\t" "v_mov_b32 v35, 0\n\t" \
  "v_mov_b32 v36, 0\n\t" "v_mov_b32 v37, 0\n\t" \
  "v_mov_b32 v38, 0\n\t" "v_mov_b32 v39, 0\n\t"

// ===== rec weight loads (flat v[10:11] addressing; r15 verbatim) =====
#define WLD(R,O) "global_load_dword v" STR(R) ", v[10:11], off offset:" STR(O) "\n\t"
#define WBUMP \
  "v_add_co_u32 v10, vcc, 0x1000, v10\n\t" \
  "v_addc_co_u32 v11, vcc, 0, v11, vcc\n\t"

#define WIN16(R0,R1,R2,R3,R4,R5,R6,R7,R8,R9,R10,R11,R12,R13,R14,R15) \
  WLD(R0,0) WLD(R1,256) WLD(R2,512) WLD(R3,768) \
  WLD(R4,1024) WLD(R5,1280) WLD(R6,1536) WLD(R7,1792) \
  WLD(R8,2048) WLD(R9,2304) WLD(R10,2560) WLD(R11,2816) \
  WLD(R12,3072) WLD(R13,3328) WLD(R14,3584) WLD(R15,3840)

#define WLOAD_A \
  WIN16(64,65,66,67,68,69,70,71,72,73,74,75,76,77,78,79) WBUMP \
  WIN16(80,81,82,83,84,85,86,87,88,89,90,91,92,93,94,95) WBUMP \
  WIN16(96,97,98,99,100,101,102,103,104,105,106,107,108,109,110,111) WBUMP \
  WIN16(112,113,114,115,116,117,118,119,120,121,122,123,124,125,126,127)

#define WLOAD_B \
  WIN16(128,129,130,131,132,133,134,135,136,137,138,139,140,141,142,143) WBUMP \
  WIN16(144,145,146,147,148,149,150,151,152,153,154,155,156,157,158,159) WBUMP \
  WIN16(160,161,162,163,164,165,166,167,168,169,170,171,172,173,174,175) WBUMP \
  WIN16(176,177,178,179,180,181,182,183,184,185,186,187,188,189,190,191)

// ===== proj weight loads (SGPR base s[56:57] + vaddr v14 = u*4) =====
#define PWLD(R,O) "global_load_dword v" STR(R) ", v14, s[56:57] offset:" STR(O) "\n\t"
#define PWBUMP "s_add_u32 s56, s56, 0x1000\n\ts_addc_u32 s57, s57, 0\n\t"

#define PWIN16(R0,R1,R2,R3,R4,R5,R6,R7,R8,R9,R10,R11,R12,R13,R14,R15) \
  PWLD(R0,0) PWLD(R1,256) PWLD(R2,512) PWLD(R3,768) \
  PWLD(R4,1024) PWLD(R5,1280) PWLD(R6,1536) PWLD(R7,1792) \
  PWLD(R8,2048) PWLD(R9,2304) PWLD(R10,2560) PWLD(R11,2816) \
  PWLD(R12,3072) PWLD(R13,3328) PWLD(R14,3584) PWLD(R15,3840)

#define PWLOAD_A \
  PWIN16(64,65,66,67,68,69,70,71,72,73,74,75,76,77,78,79) PWBUMP \
  PWIN16(80,81,82,83,84,85,86,87,88,89,90,91,92,93,94,95) PWBUMP \
  PWIN16(96,97,98,99,100,101,102,103,104,105,106,107,108,109,110,111) PWBUMP \
  PWIN16(112,113,114,115,116,117,118,119,120,121,122,123,124,125,126,127)

#define PWLOAD_B \
  PWIN16(128,129,130,131,132,133,134,135,136,137,138,139,140,141,142,143) PWBUMP \
  PWIN16(144,145,146,147,148,149,150,151,152,153,154,155,156,157,158,159) PWBUMP \
  PWIN16(160,161,162,163,164,165,166,167,168,169,170,171,172,173,174,175) PWBUMP \
  PWIN16(176,177,178,179,180,181,182,183,184,185,186,187,188,189,190,191)

// reduce accs -> v15 (sum A chains), v16 (sum B chains); v18 temp
#define PREDUCE \
  "v_add_f32 v15, v32, v33\n\t" \
  "v_add_f32 v16, v34, v35\n\t" \
  "v_add_f32 v15, v15, v16\n\t" \
  "v_add_f32 v16, v36, v37\n\t" \
  "v_add_f32 v18, v38, v39\n\t" \
  "v_add_f32 v16, v16, v18\n\t"

#define ACLOBBERS \
  "v8","v9","v10","v11","v12","v13","v14","v15","v16","v17", \
  "v28","v29", \
  "v32","v33","v34","v35","v36","v37","v38","v39","v40","v41","v42","v43", \
  "v44","v45","v46","v50","v51","v52","v53", \
  "v64","v65","v66","v67","v68","v69","v70","v71", \
  "v72","v73","v74","v75","v76","v77","v78","v79", \
  "v80","v81","v82","v83","v84","v85","v86","v87", \
  "v88","v89","v90","v91","v92","v93","v94","v95", \
  "v96","v97","v98","v99","v100","v101","v102","v103", \
  "v104","v105","v106","v107","v108","v109","v110","v111", \
  "v112","v113","v114","v115","v116","v117","v118","v119", \
  "v120","v121","v122","v123","v124","v125","v126","v127", \
  "v128","v129","v130","v131","v132","v133","v134","v135", \
  "v136","v137","v138","v139","v140","v141","v142","v143", \
  "v144","v145","v146","v147","v148","v149","v150","v151", \
  "v152","v153","v154","v155","v156","v157","v158","v159", \
  "v160","v161","v162","v163","v164","v165","v166","v167", \
  "v168","v169","v170","v171","v172","v173","v174","v175", \
  "v176","v177","v178","v179","v180","v181","v182","v183", \
  "v184","v185","v186","v187","v188","v189","v190","v191", \
  "v192","v193","v194","v195","v196","v197","v198","v199", \
  "v200","v201","v202","v203","v204","v205","v206","v207", \
  "v208","v209","v210","v211","v212","v213","v214","v215", \
  "v216","v217","v218","v219","v220","v221","v222","v223", \
  "v224","v225","v226","v227","v228","v229","v230","v231", \
  "v232","v233","v234","v235","v236","v237","v238","v239", \
  "v240","v241","v242","v243","v244","v245","v246","v247", \
  "v248","v249","v250","v251","v252","v253","v254","v255", \
  "s48","s49","s50","vcc","scc","memory"

#define PROJ_CLOBBERS \
  "v12","v14","v15","v16","v18","v26","v27","v28","v29", \
  "v32","v33","v34","v35","v36","v37","v38","v39", \
  "v40","v41","v42","v43","v44","v45","v46","v47", \
  "v48","v49","v50","v51","v52","v53","v54","v55", \
  "v64","v65","v66","v67","v68","v69","v70","v71", \
  "v72","v73","v74","v75","v76","v77","v78","v79", \
  "v80","v81","v82","v83","v84","v85","v86","v87", \
  "v88","v89","v90","v91","v92","v93","v94","v95", \
  "v96","v97","v98","v99","v100","v101","v102","v103", \
  "v104","v105","v106","v107","v108","v109","v110","v111", \
  "v112","v113","v114","v115","v116","v117","v118","v119", \
  "v120","v121","v122","v123","v124","v125","v126","v127", \
  "v128","v129","v130","v131","v132","v133","v134","v135", \
  "v136","v137","v138","v139","v140","v141","v142","v143", \
  "v144","v145","v146","v147","v148","v149","v150","v151", \
  "v152","v153","v154","v155","v156","v157","v158","v159", \
  "v160","v161","v162","v163","v164","v165","v166","v167", \
  "v168","v169","v170","v171","v172","v173","v174","v175", \
  "v176","v177","v178","v179","v180","v181","v182","v183", \
  "v184","v185","v186","v187","v188","v189","v190","v191", \
  "v192","v193","v194","v195","v196","v197","v198","v199", \
  "v200","v201","v202","v203","v204","v205","v206","v207", \
  "v208","v209","v210","v211","v212","v213","v214","v215", \
  "v216","v217","v218","v219","v220","v221","v222","v223", \
  "v224","v225","v226","v227","v228","v229","v230","v231", \
  "v232","v233","v234","v235","v236","v237","v238","v239", \
  "v240","v241","v242","v243","v244","v245","v246","v247", \
  "v248","v249","v250","v251","v252","v253","v254","v255", \
  "s40","s41","s44","s45","s56","s57","s60","s61","vcc","scc","memory"

// ---------------- Kernel 2: recurrence (r13/r15 verbatim) ----------------
// 512 blocks x 256 = 2048 waves (2/SIMD), 1 batch row per wave.
__global__ __launch_bounds__(256, 2) void rec_kernel(
    const f32x2* __restrict__ pre, const float* __restrict__ att,
    const float* __restrict__ h0,  const float* __restrict__ w_hr,
    const float* __restrict__ w_hh,const float* __restrict__ b_hh,
    float* __restrict__ out)
{
    const int u   = threadIdx.x & 63;
    const int row = (int)((blockIdx.x * blockDim.x + threadIdx.x) >> 6);

    __shared__ __align__(16) float hbuf[4][UDIM];
    const unsigned lrb = (unsigned)(unsigned long long)(&hbuf[threadIdx.x >> 6][0]);
    const unsigned lwa = lrb + 4u * (unsigned)u;

    const float* wa = w_hr + u;
    const float* wb = w_hh + u;
    const f32x2* pp = pre + (size_t)row * T_STEPS * UDIM + u;
    const float* ap = att + (size_t)row * T_STEPS;
    float*       op = out + (size_t)row * T_STEPS * UDIM + u;
    const float h0v = h0[(size_t)row * UDIM + u];
    const float bgv = b_hh[u];

    asm volatile(
        "v_mov_b32 v10, %[walo]\n\t" "v_mov_b32 v11, %[wahi]\n\t"
        WLOAD_A
        "v_mov_b32 v10, %[wblo]\n\t" "v_mov_b32 v11, %[wbhi]\n\t"
        WLOAD_B
        "v_mov_b32 v12, %[prelo]\n\t" "v_mov_b32 v13, %[prehi]\n\t"
        "v_mov_b32 v14, %[attlo]\n\t" "v_mov_b32 v15, %[atthi]\n\t"
        "v_mov_b32 v16, %[outlo]\n\t" "v_mov_b32 v17, %[outhi]\n\t"
        "v_mov_b32 v8, %[h0v]\n\t"
        "v_mov_b32 v9, %[bgv]\n\t"
        "v_mov_b32 v28, %[lwa]\n\t"
        "v_mov_b32 v29, %[lrb]\n\t"
        "global_load_dwordx2 v[40:41], v[12:13], off\n\t"
        "global_load_dword v42, v[14:15], off\n\t"
        "v_add_co_u32 v12, vcc, 0x200, v12\n\t"
        "v_addc_co_u32 v13, vcc, 0, v13, vcc\n\t"
        "v_add_co_u32 v14, vcc, 4, v14\n\t"
        "v_addc_co_u32 v15, vcc, 0, v15, vcc\n\t"
        "s_waitcnt vmcnt(0)\n\t"
        "v_mov_b32 v44, v40\n\t" "v_mov_b32 v45, v41\n\t" "v_mov_b32 v46, v42\n\t"
        "global_load_dwordx2 v[40:41], v[12:13], off\n\t"
        "global_load_dword v42, v[14:15], off\n\t"
        "v_add_co_u32 v12, vcc, 0x200, v12\n\t"
        "v_addc_co_u32 v13, vcc, 0, v13, vcc\n\t"
        "v_add_co_u32 v14, vcc, 4, v14\n\t"
        "v_addc_co_u32 v15, vcc, 0, v15, vcc\n\t"
        "ds_write_b32 v28, v8\n\t"
        "s_waitcnt lgkmcnt(0)\n\t"
        LDSREADS
        "s_movk_i32 s48, 200\n\t"
        "Lrec%=:\n\t"
        ACC_ZERO
        DOTCONSUME
        "v_add_f32 v50, v32, v33\n\t"
        "v_add_f32 v51, v34, v35\n\t"
        "v_add_f32 v52, v36, v37\n\t"
        "v_add_f32 v53, v38, v39\n\t"
        "v_add_f32 v50, v50, v51\n\t"
        "v_add_f32 v52, v52, v53\n\t"
        "v_add_f32 v50, v44, v50\n\t"              // zr
        "v_add_f32 v52, v9, v52\n\t"               // sG + bg
        "v_mul_f32 v50, 0xbfb8aa3b, v50\n\t"       // -zr*log2e
        "v_exp_f32 v50, v50\n\t"
        "s_nop 1\n\t"
        "v_add_f32 v50, 1.0, v50\n\t"
        "v_rcp_f32 v50, v50\n\t"                   // r
        "s_nop 1\n\t"
        "v_mul_f32 v52, v50, v52\n\t"
        "v_add_f32 v52, v45, v52\n\t"              // zh
        "v_mul_f32 v52, 0x4038aa3b, v52\n\t"       // zh*2*log2e
        "v_exp_f32 v52, v52\n\t"
        "s_nop 1\n\t"
        "v_add_f32 v52, 1.0, v52\n\t"
        "v_rcp_f32 v52, v52\n\t"
        "s_nop 1\n\t"
        "v_fma_f32 v52, -2.0, v52, 1.0\n\t"        // hc
        "v_sub_f32 v53, v52, v8\n\t"
        "v_fmac_f32 v8, v46, v53\n\t"              // h += av*(hc-h)
        "ds_write_b32 v28, v8\n\t"
        "s_waitcnt vmcnt(2)\n\t"
        "v_mov_b32 v43, v8\n\t"
        "global_store_dword v[16:17], v43, off\n\t"
        "v_add_co_u32 v16, vcc, 0x100, v16\n\t"
        "v_addc_co_u32 v17, vcc, 0, v17, vcc\n\t"
        "s_waitcnt vmcnt(1)\n\t"
        "v_mov_b32 v44, v40\n\t" "v_mov_b32 v45, v41\n\t" "v_mov_b32 v46, v42\n\t"
        "global_load_dwordx2 v[40:41], v[12:13], off\n\t"
        "global_load_dword v42, v[14:15], off\n\t"
        "s_sub_u32 s48, s48, 1\n\t"
        "s_cmp_ge_u32 s48, 3\n\t"
        "s_cselect_b32 s49, 0x200, 0\n\t"
        "s_cselect_b32 s50, 4, 0\n\t"
        "v_add_co_u32 v12, vcc, s49, v12\n\t"
        "v_addc_co_u32 v13, vcc, 0, v13, vcc\n\t"
        "v_add_co_u32 v14, vcc, s50, v14\n\t"
        "v_addc_co_u32 v15, vcc, 0, v15, vcc\n\t"
        "s_waitcnt lgkmcnt(0)\n\t"
        LDSREADS
        "s_cmp_lg_u32 s48, 0\n\t"
        "s_cbranch_scc1 Lrec%=\n\t"
        "s_waitcnt vmcnt(0) lgkmcnt(0)\n\t"
        :
        : [walo]"v"(PTRLO(wa)), [wahi]"v"(PTRHI(wa)),
          [wblo]"v"(PTRLO(wb)), [wbhi]"v"(PTRHI(wb)),
          [prelo]"v"(PTRLO(pp)), [prehi]"v"(PTRHI(pp)),
          [attlo]"v"(PTRLO(ap)), [atthi]"v"(PTRHI(ap)),
          [outlo]"v"(PTRLO(op)), [outhi]"v"(PTRHI(op)),
          [h0v]"v"(h0v), [bgv]"v"(bgv),
          [lwa]"v"(lwa), [lrb]"v"(lrb)
        : ACLOBBERS);
}

// ---------------- Kernel 1: projections (asm, 4-row LDS-broadcast) --------
// 1024 blocks x 256 = 4096 waves; groups strided by 4096; 25 groups/wave.
__global__ __launch_bounds__(256, 1) void proj_kernel(
    const float* __restrict__ x,  const float* __restrict__ w_ir,
    const float* __restrict__ w_ih, const float* __restrict__ b_ir,
    const float* __restrict__ b_hr, const float* __restrict__ b_ih,
    f32x2* __restrict__ pre)
{
    const int u   = threadIdx.x & 63;
    const int wid = (int)((blockIdx.x * blockDim.x + threadIdx.x) >> 6);

    __shared__ __align__(16) float xbuf[4][4][UDIM];   // 4 KB/block
    const unsigned lrb = (unsigned)(unsigned long long)(&xbuf[threadIdx.x >> 6][0][0]);
    const unsigned lwa = lrb + 4u * (unsigned)u;

    const float* xb = x   + (size_t)wid * 4 * UDIM;   // this wave's group 0
    f32x2*       pb = pre + (size_t)wid * 4 * UDIM;

    const unsigned xlo = rfl(PTRLO(xb)), xhi = rfl(PTRHI(xb));
    const unsigned plo = rfl(PTRLO(pb)), phi = rfl(PTRHI(pb));
    const unsigned wirlo = rfl(PTRLO(w_ir)), wirhi = rfl(PTRHI(w_ir));
    const unsigned wihlo = rfl(PTRLO(w_ih)), wihhi = rfl(PTRHI(w_ih));
    const float brv = b_ir[u] + b_hr[u];
    const float bhv = b_ih[u];

    asm volatile(
        // ---- bases & lane addressing ----
        "s_mov_b32 s40, %[xlo]\n\t" "s_mov_b32 s41, %[xhi]\n\t"
        "s_mov_b32 s44, %[plo]\n\t" "s_mov_b32 s45, %[phi]\n\t"
        "v_mov_b32 v28, %[lwa]\n\t"
        "v_mov_b32 v29, %[lrb]\n\t"
        "v_sub_u32 v14, v28, v29\n\t"       // u*4
        "v_lshlrev_b32 v12, 1, v14\n\t"     // u*8
        "v_mov_b32 v26, %[brv]\n\t"
        "v_mov_b32 v27, %[bhv]\n\t"
        // ---- weights: w_ir -> v64..127 (A), w_ih -> v128..191 (B) ----
        "s_mov_b32 s56, %[wirlo]\n\t" "s_mov_b32 s57, %[wirhi]\n\t"
        PWLOAD_A
        "s_mov_b32 s56, %[wihlo]\n\t" "s_mov_b32 s57, %[wihhi]\n\t"
        PWLOAD_B
        // ---- prologue: load group 0's 4 x rows; bump base; drain; stage ----
        "global_load_dword v40, v14, s[40:41]\n\t"
        "global_load_dword v41, v14, s[40:41] offset:256\n\t"
        "global_load_dword v42, v14, s[40:41] offset:512\n\t"
        "global_load_dword v43, v14, s[40:41] offset:768\n\t"
        "s_add_u32 s40, s40, 0x400000\n\t" "s_addc_u32 s41, s41, 0\n\t"
        "s_waitcnt vmcnt(0)\n\t"                      // also drains weights
        "v_mov_b32 v44, v40\n\t" "v_mov_b32 v45, v41\n\t"
        "v_mov_b32 v46, v42\n\t" "v_mov_b32 v47, v43\n\t"
        "s_movk_i32 s60, 25\n\t"
        "Lproj%=:\n\t"
        // ---- stage 4 rows in LDS; prefetch next group's x ----
        "ds_write_b32 v28, v44\n\t"
        "ds_write_b32 v28, v45 offset:256\n\t"
        "ds_write_b32 v28, v46 offset:512\n\t"
        "ds_write_b32 v28, v47 offset:768\n\t"
        "global_load_dword v40, v14, s[40:41]\n\t"
        "global_load_dword v41, v14, s[40:41] offset:256\n\t"
        "global_load_dword v42, v14, s[40:41] offset:512\n\t"
        "global_load_dword v43, v14, s[40:41] offset:768\n\t"
        "s_waitcnt lgkmcnt(0)\n\t"                    // writes visible
        // ---- row 0 ----
        LDSREADS
        ACC_ZERO
        DOTCONSUME
        PREADS1
        PREDUCE
        ACC_ZERO
        "s_waitcnt vmcnt(7)\n\t"                      // S_prev0 retired
        "v_add_f32 v48, v26, v15\n\t"
        "v_add_f32 v49, v27, v16\n\t"
        "global_store_dwordx2 v12, v[48:49], s[44:45]\n\t"
        // ---- row 1 ----
        DOTCONSUME
        PREADS2
        PREDUCE
        ACC_ZERO
        "s_waitcnt vmcnt(7)\n\t"                      // S_prev1 retired
        "v_add_f32 v50, v26, v15\n\t"
        "v_add_f32 v51, v27, v16\n\t"
        "global_store_dwordx2 v12, v[50:51], s[44:45] offset:512\n\t"
        // ---- row 2 ----
        DOTCONSUME
        PREADS3
        PREDUCE
        ACC_ZERO
        "s_waitcnt vmcnt(7)\n\t"                      // S_prev2 retired
        "v_add_f32 v52, v26, v15\n\t"
        "v_add_f32 v53, v27, v16\n\t"
        "global_store_dwordx2 v12, v[52:53], s[44:45] offset:1024\n\t"
        // ---- row 3 ----
        DOTCONSUME
        PREDUCE
        "s_waitcnt vmcnt(7)\n\t"                      // S_prev3 retired
        "v_add_f32 v54, v26, v15\n\t"
        "v_add_f32 v55, v27, v16\n\t"
        "global_store_dwordx2 v12, v[54:55], s[44:45] offset:1536\n\t"
        // ---- bottom: bump bases (x clamped), rotate prefetch ----
        "s_sub_u32 s60, s60, 1\n\t"
        "s_cmp_ge_u32 s60, 2\n\t"
        "s_cselect_b32 s61, 0x400000, 0\n\t"
        "s_add_u32 s40, s40, s61\n\t" "s_addc_u32 s41, s41, 0\n\t"
        "s_add_u32 s44, s44, 0x800000\n\t" "s_addc_u32 s45, s45, 0\n\t"
        "s_waitcnt vmcnt(4)\n\t"                      // 4 prefetch loads done
        "v_mov_b32 v44, v40\n\t" "v_mov_b32 v45, v41\n\t"
        "v_mov_b32 v46, v42\n\t" "v_mov_b32 v47, v43\n\t"
        "s_cmp_lg_u32 s60, 0\n\t"
        "s_cbranch_scc1 Lproj%=\n\t"
        "s_waitcnt vmcnt(0) lgkmcnt(0)\n\t"
        :
        : [xlo]"s"(xlo), [xhi]"s"(xhi),
          [plo]"s"(plo), [phi]"s"(phi),
          [wirlo]"s"(wirlo), [wirhi]"s"(wirhi),
          [wihlo]"s"(wihlo), [wihhi]"s"(wihhi),
          [brv]"v"(brv), [bhv]"v"(bhv),
          [lwa]"v"(lwa), [lrb]"v"(lrb)
        : PROJ_CLOBBERS);
}

// ---------------- Fallback: fused kernel (small ws) ----------------
__global__ __launch_bounds__(256) void agru_fused_kernel(
    const float* __restrict__ x, const float* __restrict__ att,
    const float* __restrict__ h0,
    const float* __restrict__ w_ir, const float* __restrict__ w_hr,
    const float* __restrict__ b_ir, const float* __restrict__ b_hr,
    const float* __restrict__ w_ih, const float* __restrict__ w_hh,
    const float* __restrict__ b_ih, const float* __restrict__ b_hh,
    float* __restrict__ out)
{
    __shared__ float lds[4 * UDIM * UDIM];
    const int tid = threadIdx.x;
    #pragma unroll
    for (int i = 0; i < 16; ++i) {
        int e = tid + 256 * i;
        lds[e] = w_ir[e]; lds[4096 + e] = w_ih[e];
        lds[8192 + e] = w_hr[e]; lds[12288 + e] = w_hh[e];
    }
    __syncthreads();

    const int wave = tid >> 6;
    const int u = tid & 63;
    const int r0 = blockIdx.x * 8 + wave * 2;
    const int r1 = r0 + 1;

    float h_0 = h0[r0 * UDIM + u];
    float h_1 = h0[r1 * UDIM + u];
    const float bR = b_ir[u] + b_hr[u];
    const float bH = b_ih[u];
    const float bG = b_hh[u];

    const float* xp0 = x + (long)r0 * T_STEPS * UDIM + u;
    const float* xp1 = x + (long)r1 * T_STEPS * UDIM + u;
    const float* ap0 = att + (long)r0 * T_STEPS;
    const float* ap1 = att + (long)r1 * T_STEPS;
    float* op0 = out + (long)r0 * T_STEPS * UDIM + u;
    float* op1 = out + (long)r1 * T_STEPS * UDIM + u;

    float xv0 = xp0[0], xv1 = xp1[0], a0 = ap0[0], a1 = ap1[0];

    for (int t = 0; t < T_STEPS; ++t) {
        const int tn = (t + 1 < T_STEPS) ? (t + 1) : t;
        float nxv0 = xp0[(long)tn * UDIM], nxv1 = xp1[(long)tn * UDIM];
        float na0 = ap0[tn], na1 = ap1[tn];

        float accR0 = bR, accR1 = bR, accH0 = bH, accH1 = bH, accG0 = bG, accG1 = bG;
        #pragma unroll
        for (int j = 0; j < 64; ++j) {
            const float wir = lds[j * 64 + u];
            const float wih = lds[4096 + j * 64 + u];
            const float whr = lds[8192 + j * 64 + u];
            const float whh = lds[12288 + j * 64 + u];
            const float xj0 = lane_bcast(xv0, j);
            const float xj1 = lane_bcast(xv1, j);
            const float hj0 = lane_bcast(h_0, j);
            const float hj1 = lane_bcast(h_1, j);
            accR0 = fmaf(xj0, wir, accR0); accR0 = fmaf(hj0, whr, accR0);
            accH0 = fmaf(xj0, wih, accH0); accG0 = fmaf(hj0, whh, accG0);
            accR1 = fmaf(xj1, wir, accR1); accR1 = fmaf(hj1, whr, accR1);
            accH1 = fmaf(xj1, wih, accH1); accG1 = fmaf(hj1, whh, accG1);
        }
        const float r0g = fast_sigmoid(accR0);
        const float r1g = fast_sigmoid(accR1);
        const float hc0 = fast_tanh(fmaf(r0g, accG0, accH0));
        const float hc1 = fast_tanh(fmaf(r1g, accG1, accH1));
        h_0 = fmaf(a0, hc0 - h_0, h_0);
        h_1 = fmaf(a1, hc1 - h_1, h_1);
        op0[(long)t * UDIM] = h_0;
        op1[(long)t * UDIM] = h_1;
        xv0 = nxv0; xv1 = nxv1; a0 = na0; a1 = na1;
    }
}

extern "C" void kernel_launch(void* const* d_in, const int* in_sizes, int n_in,
                              void* d_out, int out_size, void* d_ws, size_t ws_size,
                              hipStream_t stream) {
    (void)in_sizes; (void)n_in; (void)out_size;

    const float* x    = (const float*)d_in[0];
    const float* att  = (const float*)d_in[1];
    const float* h0   = (const float*)d_in[2];
    const float* w_ir = (const float*)d_in[3];
    const float* w_hr = (const float*)d_in[4];
    const float* b_ir = (const float*)d_in[5];
    const float* b_hr = (const float*)d_in[6];
    const float* w_ih = (const float*)d_in[7];
    const float* w_hh = (const float*)d_in[8];
    const float* b_ih = (const float*)d_in[9];
    const float* b_hh = (const float*)d_in[10];
    float* out = (float*)d_out;

    const size_t pre_bytes = (size_t)NROWS * UDIM * sizeof(f32x2); // 210 MB

    if (ws_size >= pre_bytes) {
        f32x2* pre = (f32x2*)d_ws;
        proj_kernel<<<dim3(1024), dim3(256), 0, stream>>>(
            x, w_ir, w_ih, b_ir, b_hr, b_ih, pre);
        rec_kernel<<<dim3(512), dim3(256), 0, stream>>>(
            pre, att, h0, w_hr, w_hh, b_hh, out);
    } else {
        agru_fused_kernel<<<dim3(256), dim3(256), 0, stream>>>(
            x, att, h0, w_ir, w_hr, b_ir, b_hr, w_ih, w_hh, b_ih, b_hh, out);
    }
}